// Round 11
// baseline (204.743 us; speedup 1.0000x reference)
//
#include <hip/hip_runtime.h>

// Fully fused 100x100 sliding mean: x[32][1][1124][1124] f32 -> out[32][1][1025][1025] f32.
// The horizontal-sum intermediate never touches HBM (R4 retry, execution fixed):
//  - block = 256 output cols x one row-band; ALL 256 threads active every phase
//  - CH=8 input rows per phase, 3 barriers/phase (~102 barriers/block vs R4's 204)
//  - h-sum via ps (sums-of-4) -> qs (sliding sums-of-16): 7 uniform stride-1 LDS
//    reads per 100-tap sum; conflict-free by construction
//  - no srow in LDS: ps computed from register-prefetched global f32x4; the
//    slide's lo/hi re-reads are L1 hits (same lines, same phase)
//  - vertical window = f16 ring[108][264] in LDS; per-thread running sum
// LDS 62.8 KB -> 2 blocks/CU. Grid 4 strips x 6 bands x 32 = 768 blocks.
// Ideal traffic 162R + 134W = 296 MB (~50 us floor) + band-halo re-reads.

#define H_IN   1124
#define W_IN   1124
#define KWIN   100
#define W_OUT  1025
#define H_OUT  1025
#define NSTRIP 4
#define NBAND  6
#define BR     171    // out rows per band (last band: 170)
#define CH     8      // input rows per phase
#define RS     108    // ring slots (100 window + CH in flight)
#define RW     264    // ring row width in halves (256 used + col-1024 slot + pad)
#define PSW    92     // ps row stride (90 used)
#define QSW    88     // qs row stride (86 used)

typedef float    f32x4 __attribute__((ext_vector_type(4)));
typedef _Float16 f16x4 __attribute__((ext_vector_type(4)));

__global__ __launch_bounds__(256) void fused_box_kernel(
    const float* __restrict__ x, float* __restrict__ out)
{
    __shared__ float    ps[CH][PSW];     // 2944 B
    __shared__ float    qs[CH][QSW];     // 2816 B
    __shared__ _Float16 ring[RS][RW];    // 57024 B

    const int tid   = threadIdx.x;
    const int strip = blockIdx.x;
    const int band  = blockIdx.y;
    const int b     = blockIdx.z;

    const int  c0     = strip * 256;
    const bool s3     = (strip == NSTRIP - 1);      // also owns col 1024
    const int  r0out  = band * BR;
    const int  r1out  = min(r0out + BR, H_OUT);
    const int  r0in   = r0out;
    const int  r1in   = r1out + KWIN - 1;           // exclusive input-row bound
    const int  cbase4 = c0 >> 2;

    const f32x4* x4 = (const f32x4*)x;
    const size_t rowstride4 = 281;                  // 1124 floats = 281 f32x4
    const size_t bbase = (size_t)b * H_IN * rowstride4;

    // prefetch task mapping: 720 tasks = 8 rows x 90 f32x4-cols
    const int u0r = tid / 90,        u0j = tid % 90;
    const int u1r = (tid + 256)/90,  u1j = (tid + 256)%90;
    const int u2r = (tid + 512)/90,  u2j = (tid + 512)%90;   // valid if tid<208

    int gj0 = cbase4 + u0j; if (gj0 > 280) gj0 = 280;
    int gj1 = cbase4 + u1j; if (gj1 > 280) gj1 = 280;
    int gj2 = cbase4 + u2j; if (gj2 > 280) gj2 = 280;

    // prologue: prefetch rows r0in..r0in+7 (nin >= 269, no row guard needed)
    f32x4 pf0 = x4[bbase + (size_t)(r0in + u0r) * rowstride4 + gj0];
    f32x4 pf1 = x4[bbase + (size_t)(r0in + u1r) * rowstride4 + gj1];
    f32x4 pf2 = pf0;
    if (tid < 208) pf2 = x4[bbase + (size_t)(r0in + u2r) * rowstride4 + gj2];

    float s = 0.f, s8 = 0.f;
    const float scale = 1.0f / 10000.0f;

    for (int ra = r0in; ra < r1in; ra += CH) {
        const int sl0 = (ra - r0in) % RS;           // ring slot of row ra

        // ---- step 1: ps from prefetched registers ----
        if (ra + u0r < r1in) ps[u0r][u0j] = pf0[0] + pf0[1] + pf0[2] + pf0[3];
        if (ra + u1r < r1in) ps[u1r][u1j] = pf1[0] + pf1[1] + pf1[2] + pf1[3];
        if (tid < 208 && ra + u2r < r1in)
            ps[u2r][u2j] = pf2[0] + pf2[1] + pf2[2] + pf2[3];
        __syncthreads();                            // bar1: ps visible

        // ---- step 2: qs (sliding sums of 16) + prefetch next chunk ----
        {
            int u = tid;
            #pragma unroll
            for (int k = 0; k < 3; ++k, u += 256) {
                if (u < 688) {                      // 8 x 86 tasks
                    int r = u / 86, j = u % 86;
                    if (ra + r < r1in)
                        qs[r][j] = ps[r][j] + ps[r][j+1] + ps[r][j+2] + ps[r][j+3];
                }
            }
            const int rb = ra + CH;
            if (rb < r1in) {
                if (rb + u0r < r1in)
                    pf0 = x4[bbase + (size_t)(rb + u0r) * rowstride4 + gj0];
                if (rb + u1r < r1in)
                    pf1 = x4[bbase + (size_t)(rb + u1r) * rowstride4 + gj1];
                if (tid < 208 && rb + u2r < r1in)
                    pf2 = x4[bbase + (size_t)(rb + u2r) * rowstride4 + gj2];
            }
        }
        __syncthreads();                            // bar2: qs visible

        // ---- step 3: 100-tap h-sums + slide -> f16 ring ----
        {
            #pragma unroll
            for (int k = 0; k < 2; ++k) {
                const int u = tid + k * 256;        // 512 tasks = 8 rows x 64 chunks
                const int r = u >> 6, c = u & 63;
                const int rin = ra + r;
                if (rin < r1in) {
                    float S = qs[r][c] + qs[r][c+4] + qs[r][c+8]
                            + qs[r][c+12] + qs[r][c+16] + qs[r][c+20]
                            + ps[r][c+24];
                    const f32x4* rp = x4 + bbase + (size_t)rin * rowstride4
                                    + cbase4 + c;
                    f32x4 lo = rp[0];               // x[c0+4c .. +3]   (L1 hit)
                    f32x4 hi = rp[25];              // x[c0+4c+100..+103]
                    float h1 = S  + hi[0] - lo[0];
                    float h2 = h1 + hi[1] - lo[1];
                    float h3 = h2 + hi[2] - lo[2];
                    int slot = sl0 + r; if (slot >= RS) slot -= RS;
                    *(f16x4*)&ring[slot][4 * c] =
                        f16x4{ (_Float16)S, (_Float16)h1,
                               (_Float16)h2, (_Float16)h3 };
                }
            }
            if (s3 && tid < CH) {                   // col 1024 (aligned, no slide)
                const int rin = ra + tid;
                if (rin < r1in) {
                    float S = qs[tid][64] + qs[tid][68] + qs[tid][72]
                            + qs[tid][76] + qs[tid][80] + qs[tid][84]
                            + ps[tid][88];
                    int slot = sl0 + tid; if (slot >= RS) slot -= RS;
                    ring[slot][256] = (_Float16)S;
                }
            }
        }
        __syncthreads();                            // bar3: ring visible

        // ---- step 4: vertical running sum + emit (thread = one column) ----
        {
            #pragma unroll
            for (int q2 = 0; q2 < CH; ++q2) {
                const int rin = ra + q2;
                if (rin >= r1in) break;
                const int rl = rin - r0in;
                int slot = sl0 + q2; if (slot >= RS) slot -= RS;
                s += (float)ring[slot][tid];
                if (s3 && tid == 255) s8 += (float)ring[slot][256];
                if (rl >= KWIN) {
                    int sub = slot - KWIN; if (sub < 0) sub += RS;
                    s -= (float)ring[sub][tid];
                    if (s3 && tid == 255) s8 -= (float)ring[sub][256];
                }
                if (rl >= KWIN - 1) {
                    const int orow = rin - (KWIN - 1);
                    float* q = out + ((size_t)b * H_OUT + orow) * W_OUT + c0 + tid;
                    __builtin_nontemporal_store(s * scale, q);
                    if (s3 && tid == 255)
                        __builtin_nontemporal_store(s8 * scale, q + 1);
                }
            }
        }
        // no trailing barrier needed: next phase's ps writes don't race step 4
        // (step-3(N+1) ring writes are two barriers away from step-4(N) reads)
    }
}

extern "C" void kernel_launch(void* const* d_in, const int* in_sizes, int n_in,
                              void* d_out, int out_size, void* d_ws, size_t ws_size,
                              hipStream_t stream) {
    const float* x = (const float*)d_in[0];
    float* out     = (float*)d_out;
    (void)d_ws; (void)ws_size;

    dim3 grid(NSTRIP, NBAND, 32);
    fused_box_kernel<<<grid, 256, 0, stream>>>(x, out);
}

// Round 12
// 130.267 us; speedup vs baseline: 1.5717x; 1.5717x over previous
//
#include <hip/hip_runtime.h>

// 100x100 sliding mean over x[32][1][1124][1124] f32 -> out[32][1][1025][1025] f32.
// Pass H (R9-validated, ~43us): horizontal 100-sum -> T (f16, stride 1032) via
//   three-level LDS partials (7 uniform LDS reads per 100-tap sum).
// Pass V (new): per-column cumsum + LDS DELAY RING. out[i] = C[i+99] - C[i-1];
//   C from 100 rows ago lives in a per-column LDS ring (f16, [100][260], 52KB,
//   no barriers, uniform-slot -> conflict-free). T is read ONCE per row per
//   band (the running-sum "subtract stream" re-read is eliminated):
//   nominal reads 220 -> 106 MB.

#define H_IN    1124
#define W_IN    1124
#define KWIN    100
#define W_OUT   1025
#define H_OUT   1025
#define TSTR    1032   // T row stride in halves (2064 B -> rows 16B-aligned)
#define NBANDS  6
#define BANDR   171    // 6*171 = 1026 >= 1025 (last band 170)
#define RSLOT   100
#define RW      260    // ring row width in halves (256 cols + col-1024 slot + pad)

typedef float    f32x4 __attribute__((ext_vector_type(4)));
typedef _Float16 f16x4 __attribute__((ext_vector_type(4)));

struct alignas(8) h4 { _Float16 a, b, c, d; };

// ---------------- Pass H: one block per input row, f16 T output -------------
__global__ __launch_bounds__(256) void hslide_kernel(
    const float* __restrict__ x,     // [g*1124][1124]
    _Float16* __restrict__ T)        // [g*1124][TSTR]
{
    __shared__ float srow[W_IN];
    __shared__ float ps[284];        // ps[j] = srow[4j..4j+3], j < 281
    __shared__ float qs[280];        // qs[j] = ps[j]+..+ps[j+3]

    const int row = blockIdx.x;
    const int tid = threadIdx.x;
    const f32x4* xr4 = (const f32x4*)(x + (size_t)row * W_IN);

    for (int i = tid; i < 281; i += 256)
        ((f32x4*)srow)[i] = __builtin_nontemporal_load(xr4 + i);
    __syncthreads();

    f32x4 lo = ((const f32x4*)srow)[tid];
    const float myps = lo[0] + lo[1] + lo[2] + lo[3];
    ps[tid] = myps;
    float myps2 = 0.f;
    if (tid < 25) {
        f32x4 v = ((const f32x4*)srow)[256 + tid];
        myps2 = v[0] + v[1] + v[2] + v[3];
        ps[256 + tid] = myps2;
    }
    __syncthreads();

    qs[tid] = myps + ps[tid + 1] + ps[tid + 2] + ps[tid + 3];
    if (tid < 22)
        qs[256 + tid] = myps2 + ps[257 + tid] + ps[258 + tid] + ps[259 + tid];
    __syncthreads();

    _Float16* trow = T + (size_t)row * TSTR;
    {
        float s = ps[tid + 24];
        #pragma unroll
        for (int i = 0; i < 6; ++i) s += qs[tid + 4 * i];   // ps[tid..tid+23]
        f32x4 hi = ((const f32x4*)srow)[tid + 25];
        float s1 = s  + hi[0] - lo[0];
        float s2 = s1 + hi[1] - lo[1];
        float s3 = s2 + hi[2] - lo[2];
        *(h4*)(trow + 4 * tid) = h4{ (_Float16)s, (_Float16)s1,
                                     (_Float16)s2, (_Float16)s3 };
        if (tid == 255) {                                   // col 1024 + zero pads
            float t = ps[280];
            #pragma unroll
            for (int i = 0; i < 6; ++i) t += qs[256 + 4 * i];
            *(h4*)(trow + 1024) = h4{ (_Float16)t, (_Float16)0.f,
                                      (_Float16)0.f, (_Float16)0.f };
            *(h4*)(trow + 1028) = h4{ (_Float16)0.f, (_Float16)0.f,
                                      (_Float16)0.f, (_Float16)0.f };
        }
    }
}

// ---------------- Pass V: per-column cumsum + LDS delay ring ----------------
// grid (4 strips, NBANDS, g), block 256; thread = one column (strip*256+tid).
// strip 3 / tid 255 also owns col 1024. No __syncthreads() anywhere.
__global__ __launch_bounds__(256) void vslide_kernel(
    const _Float16* __restrict__ T,  // [g*1124][TSTR]
    float* __restrict__ out)         // [g][1025][1025]
{
    __shared__ _Float16 ring[RSLOT][RW];

    const int tid   = threadIdx.x;
    const int strip = blockIdx.x;
    const int band  = blockIdx.y;
    const int b     = blockIdx.z;
    const int r0    = band * BANDR;
    const int nr    = min(BANDR, H_OUT - r0);
    if (nr <= 0) return;
    const int nin   = nr + KWIN - 1;            // input rows this band

    const int col   = strip * 256 + tid;
    const bool xtra = (strip == 3) && (tid == 255);   // col 1023 + col 1024
    const float scale = 1.0f / (float)(KWIN * KWIN);

    const _Float16* p = T + ((size_t)b * H_IN + r0) * TSTR + col;
    float* qout       = out + ((size_t)b * H_OUT + r0) * W_OUT + col;

    float s = 0.f, s2 = 0.f;
    int slot = 0;
    int rl = 0;

    auto step = [&](float vf, float v2f) {
        s += vf;
        if (xtra) s2 += v2f;
        if (rl >= KWIN) {
            float old = (float)ring[slot][tid];
            __builtin_nontemporal_store((s - old) * scale, qout);
            if (xtra) {
                float old2 = (float)ring[slot][256];
                __builtin_nontemporal_store((s2 - old2) * scale, qout + 1);
            }
            qout += W_OUT;
        } else if (rl == KWIN - 1) {
            __builtin_nontemporal_store(s * scale, qout);
            if (xtra) __builtin_nontemporal_store(s2 * scale, qout + 1);
            qout += W_OUT;
        }
        ring[slot][tid] = (_Float16)s;
        if (xtra) ring[slot][256] = (_Float16)s2;
        if (++slot == RSLOT) slot = 0;
        ++rl;
    };

    // main: batches of 16 independent scalar loads (32 B in flight/thread)
    for (; rl + 16 <= nin; ) {
        _Float16 v[16], v2[16];
        #pragma unroll
        for (int j = 0; j < 16; ++j) v[j] = p[(size_t)(rl + j) * TSTR];
        if (xtra) {
            #pragma unroll
            for (int j = 0; j < 16; ++j) v2[j] = p[(size_t)(rl + j) * TSTR + 1];
        }
        #pragma unroll
        for (int j = 0; j < 16; ++j) step((float)v[j], xtra ? (float)v2[j] : 0.f);
    }
    // tail
    for (; rl < nin; ) {
        _Float16 v  = p[(size_t)rl * TSTR];
        _Float16 v2 = xtra ? p[(size_t)rl * TSTR + 1] : (_Float16)0.f;
        step((float)v, (float)v2);
    }
}

extern "C" void kernel_launch(void* const* d_in, const int* in_sizes, int n_in,
                              void* d_out, int out_size, void* d_ws, size_t ws_size,
                              hipStream_t stream) {
    const float* x = (const float*)d_in[0];
    float* out     = (float*)d_out;
    _Float16* ws   = (_Float16*)d_ws;

    const int B = 32;
    const size_t perBatchT = (size_t)H_IN * TSTR * sizeof(_Float16);  // ~2.32 MB

    int G = (int)(ws_size / perBatchT);
    if (G > B) G = B;
    if (G < 1) G = 1;

    for (int b0 = 0; b0 < B; b0 += G) {
        const int g = (B - b0 < G) ? (B - b0) : G;

        hslide_kernel<<<g * H_IN, 256, 0, stream>>>(
            x + (size_t)b0 * H_IN * W_IN, ws);

        dim3 vgrid(4, NBANDS, g);
        vslide_kernel<<<vgrid, 256, 0, stream>>>(
            ws, out + (size_t)b0 * H_OUT * W_OUT);
    }
}

// Round 13
// 125.030 us; speedup vs baseline: 1.6375x; 1.0419x over previous
//
#include <hip/hip_runtime.h>

// 100x100 sliding mean over x[32][1][1124][1124] f32 -> out[32][1][1025][1025] f32.
// Pass H (R9-validated): horizontal 100-sum -> T (f16, stride 1032) via
//   three-level LDS partials (7 uniform LDS reads per 100-tap sum).
// Pass V (R9-validated): vertical 100-sum + 1e-4 scale, f16x4 loads, batch-4/8
//   steady, NT out stores.
// NEW this round: G capped at 16 -> two hslide/vslide pairs. Per pair the
// working set (x 81 + T 37 reused + out 67 NT) fits the 256 MB Infinity Cache,
// so vslide reads T L3-warm instead of from HBM (R3 measured full-size vslide
// fetching all of T from HBM; 370 MB full-run set > L3).

#define H_IN    1124
#define W_IN    1124
#define KWIN    100
#define W_OUT   1025
#define H_OUT   1025
#define TSTR    1032   // T row stride in halves (2064 B -> rows 16B-aligned)
#define NBANDS  13
#define BANDR   79     // 13*79 = 1027 >= 1025

typedef float    f32x4 __attribute__((ext_vector_type(4)));
typedef _Float16 f16x4 __attribute__((ext_vector_type(4)));

struct alignas(8) h4 { _Float16 a, b, c, d; };

// ---------------- Pass H: one block per input row, f16 T output -------------
__global__ __launch_bounds__(256) void hslide_kernel(
    const float* __restrict__ x,     // [g*1124][1124]
    _Float16* __restrict__ T)        // [g*1124][TSTR]
{
    __shared__ float srow[W_IN];
    __shared__ float ps[284];        // ps[j] = srow[4j..4j+3], j < 281
    __shared__ float qs[280];        // qs[j] = ps[j]+..+ps[j+3]

    const int row = blockIdx.x;
    const int tid = threadIdx.x;
    const f32x4* xr4 = (const f32x4*)(x + (size_t)row * W_IN);

    for (int i = tid; i < 281; i += 256)
        ((f32x4*)srow)[i] = __builtin_nontemporal_load(xr4 + i);
    __syncthreads();

    f32x4 lo = ((const f32x4*)srow)[tid];
    const float myps = lo[0] + lo[1] + lo[2] + lo[3];
    ps[tid] = myps;
    float myps2 = 0.f;
    if (tid < 25) {
        f32x4 v = ((const f32x4*)srow)[256 + tid];
        myps2 = v[0] + v[1] + v[2] + v[3];
        ps[256 + tid] = myps2;
    }
    __syncthreads();

    qs[tid] = myps + ps[tid + 1] + ps[tid + 2] + ps[tid + 3];
    if (tid < 22)
        qs[256 + tid] = myps2 + ps[257 + tid] + ps[258 + tid] + ps[259 + tid];
    __syncthreads();

    _Float16* trow = T + (size_t)row * TSTR;
    {
        float s = ps[tid + 24];
        #pragma unroll
        for (int i = 0; i < 6; ++i) s += qs[tid + 4 * i];   // ps[tid..tid+23]
        f32x4 hi = ((const f32x4*)srow)[tid + 25];
        float s1 = s  + hi[0] - lo[0];
        float s2 = s1 + hi[1] - lo[1];
        float s3 = s2 + hi[2] - lo[2];
        *(h4*)(trow + 4 * tid) = h4{ (_Float16)s, (_Float16)s1,
                                     (_Float16)s2, (_Float16)s3 };
        if (tid == 255) {                                   // col 1024 + zero pads
            float t = ps[280];
            #pragma unroll
            for (int i = 0; i < 6; ++i) t += qs[256 + 4 * i];
            *(h4*)(trow + 1024) = h4{ (_Float16)t, (_Float16)0.f,
                                      (_Float16)0.f, (_Float16)0.f };
            *(h4*)(trow + 1028) = h4{ (_Float16)0.f, (_Float16)0.f,
                                      (_Float16)0.f, (_Float16)0.f };
        }
    }
}

// ---------------- Pass V: f16x4 cached loads, batch-4 steady, NT stores -----
// grid (2 strips, NBANDS, g), block 128. Thread owns cols strip*512+4*tid..+3;
// strip 1 / tid 127 additionally owns col 1024 (via the f16x4 at +4: pad cols
// 1025..1027 are zeros written by hslide).
__global__ __launch_bounds__(128) void vslide_kernel(
    const _Float16* __restrict__ T,  // [g*1124][TSTR]
    float* __restrict__ out)         // [g][1025][1025]
{
    const int tid   = threadIdx.x;
    const int strip = blockIdx.x;
    const int band  = blockIdx.y;
    const int b     = blockIdx.z;
    const int r0    = band * BANDR;
    const int nr    = min(BANDR, H_OUT - r0);
    if (nr <= 0) return;

    const int w0 = strip * 512 + tid * 4;
    const bool xtra = (strip == 1) && (tid == 127);     // w0 == 1020
    const float scale = 1.0f / (float)(KWIN * KWIN);

    const _Float16* base = T + ((size_t)b * H_IN + r0) * TSTR + w0;

    float s0 = 0.f, s1 = 0.f, s2 = 0.f, s3 = 0.f, s8 = 0.f;

    // ---- prologue: rows r0..r0+99, batches of 8 independent 8B loads ----
    {
        const _Float16* p = base;
        for (int cg = 0; cg < 12; ++cg) {               // 96 rows
            f16x4 v[8];
            #pragma unroll
            for (int j = 0; j < 8; ++j)
                v[j] = *(const f16x4*)(p + (size_t)j * TSTR);
            f16x4 vc[8];
            if (xtra) {
                #pragma unroll
                for (int j = 0; j < 8; ++j)
                    vc[j] = *(const f16x4*)(p + (size_t)j * TSTR + 4);
            }
            #pragma unroll
            for (int j = 0; j < 8; ++j) {
                s0 += (float)v[j][0]; s1 += (float)v[j][1];
                s2 += (float)v[j][2]; s3 += (float)v[j][3];
            }
            if (xtra) {
                #pragma unroll
                for (int j = 0; j < 8; ++j) s8 += (float)vc[j][0];
            }
            p += (size_t)8 * TSTR;
        }
        #pragma unroll
        for (int j = 0; j < 4; ++j) {                   // 4 remaining rows
            f16x4 v = *(const f16x4*)(p + (size_t)j * TSTR);
            s0 += (float)v[0]; s1 += (float)v[1];
            s2 += (float)v[2]; s3 += (float)v[3];
            if (xtra) s8 += (float)*(p + (size_t)j * TSTR + 4);
        }
    }

    float* q = out + ((size_t)b * H_OUT + r0) * W_OUT + w0;
    __builtin_nontemporal_store(s0 * scale, q + 0);
    __builtin_nontemporal_store(s1 * scale, q + 1);
    __builtin_nontemporal_store(s2 * scale, q + 2);
    __builtin_nontemporal_store(s3 * scale, q + 3);
    if (xtra) __builtin_nontemporal_store(s8 * scale, q + 4);   // col 1024
    q += W_OUT;

    // ---- steady: batches of 4 steps (8 loads in flight), then remainder ----
    const _Float16* pa = base + (size_t)KWIN * TSTR;
    const _Float16* pd = base;
    const int steps = nr - 1;
    int i = 0;
    for (; i + 4 <= steps; i += 4) {
        f16x4 a[4], d[4];
        #pragma unroll
        for (int j = 0; j < 4; ++j) {
            a[j] = *(const f16x4*)(pa + (size_t)j * TSTR);
            d[j] = *(const f16x4*)(pd + (size_t)j * TSTR);
        }
        f16x4 ac[4], dc[4];
        if (xtra) {
            #pragma unroll
            for (int j = 0; j < 4; ++j) {
                ac[j] = *(const f16x4*)(pa + (size_t)j * TSTR + 4);
                dc[j] = *(const f16x4*)(pd + (size_t)j * TSTR + 4);
            }
        }
        #pragma unroll
        for (int j = 0; j < 4; ++j) {
            s0 += (float)a[j][0] - (float)d[j][0];
            s1 += (float)a[j][1] - (float)d[j][1];
            s2 += (float)a[j][2] - (float)d[j][2];
            s3 += (float)a[j][3] - (float)d[j][3];
            __builtin_nontemporal_store(s0 * scale, q + 0);
            __builtin_nontemporal_store(s1 * scale, q + 1);
            __builtin_nontemporal_store(s2 * scale, q + 2);
            __builtin_nontemporal_store(s3 * scale, q + 3);
            if (xtra) {
                s8 += (float)ac[j][0] - (float)dc[j][0];
                __builtin_nontemporal_store(s8 * scale, q + 4);
            }
            q += W_OUT;
        }
        pa += (size_t)4 * TSTR;
        pd += (size_t)4 * TSTR;
    }
    for (; i < steps; ++i) {
        f16x4 a = *(const f16x4*)pa, d = *(const f16x4*)pd;
        s0 += (float)a[0] - (float)d[0];
        s1 += (float)a[1] - (float)d[1];
        s2 += (float)a[2] - (float)d[2];
        s3 += (float)a[3] - (float)d[3];
        __builtin_nontemporal_store(s0 * scale, q + 0);
        __builtin_nontemporal_store(s1 * scale, q + 1);
        __builtin_nontemporal_store(s2 * scale, q + 2);
        __builtin_nontemporal_store(s3 * scale, q + 3);
        if (xtra) {
            s8 += (float)*(pa + 4) - (float)*(pd + 4);
            __builtin_nontemporal_store(s8 * scale, q + 4);
        }
        pa += TSTR; pd += TSTR; q += W_OUT;
    }
}

extern "C" void kernel_launch(void* const* d_in, const int* in_sizes, int n_in,
                              void* d_out, int out_size, void* d_ws, size_t ws_size,
                              hipStream_t stream) {
    const float* x = (const float*)d_in[0];
    float* out     = (float*)d_out;
    _Float16* ws   = (_Float16*)d_ws;

    const int B = 32;
    const size_t perBatchT = (size_t)H_IN * TSTR * sizeof(_Float16);  // ~2.32 MB

    int G = (int)(ws_size / perBatchT);
    if (G > 16) G = 16;   // slice so each pair's working set fits the 256MB L3
    if (G < 1) G = 1;

    for (int b0 = 0; b0 < B; b0 += G) {
        const int g = (B - b0 < G) ? (B - b0) : G;

        hslide_kernel<<<g * H_IN, 256, 0, stream>>>(
            x + (size_t)b0 * H_IN * W_IN, ws);

        dim3 vgrid(2, NBANDS, g);
        vslide_kernel<<<vgrid, 128, 0, stream>>>(
            ws, out + (size_t)b0 * H_OUT * W_OUT);
    }
}

// Round 14
// 108.245 us; speedup vs baseline: 1.8915x; 1.1551x over previous
//
#include <hip/hip_runtime.h>

// 100x100 sliding mean over x[32][1][1124][1124] f32 -> out[32][1][1025][1025] f32.
// Pass H: horizontal 100-sum via three-level LDS partials (R9-validated) ->
//   T' stored TILED: [b][8 tiles][1124 rows][128 cols] f16 (tile row = 256 B),
//   plus slim Tc[b][1124] for column 1024.
// Pass V: vertical 100-sum + 1e-4 scale. With the tiled layout a band walk
//   reads each tile BYTE-SEQUENTIALLY (256 B per row visit, rows adjacent in
//   memory) -- same access signature as the 5.9 TB/s hslide, instead of the
//   2064-B-stride hop that pinned every row-major vslide variant at 4.3 TB/s.

#define H_IN    1124
#define W_IN    1124
#define KWIN    100
#define W_OUT   1025
#define H_OUT   1025
#define NBANDS  6
#define BANDR   171    // 6*171 = 1026 >= 1025 (last band 170)
#define TROW    128    // tile width in halves (256 B)

typedef float    f32x4 __attribute__((ext_vector_type(4)));
typedef _Float16 f16x2 __attribute__((ext_vector_type(2)));

struct alignas(8) h4 { _Float16 a, b, c, d; };

// ---------------- Pass H: one block per input row, tiled f16 T output -------
// grid (H_IN, g), block 256.
__global__ __launch_bounds__(256) void hslide_kernel(
    const float* __restrict__ x,     // [g][1124][1124]
    _Float16* __restrict__ Tt,       // [g][8][1124][128]
    _Float16* __restrict__ Tc)       // [g][1124]
{
    __shared__ float srow[W_IN];
    __shared__ float ps[284];        // ps[j] = srow[4j..4j+3], j < 281
    __shared__ float qs[280];        // qs[j] = ps[j]+..+ps[j+3]

    const int row = blockIdx.x;
    const int b   = blockIdx.y;
    const int tid = threadIdx.x;
    const f32x4* xr4 = (const f32x4*)(x + ((size_t)b * H_IN + row) * W_IN);

    for (int i = tid; i < 281; i += 256)
        ((f32x4*)srow)[i] = __builtin_nontemporal_load(xr4 + i);
    __syncthreads();

    f32x4 lo = ((const f32x4*)srow)[tid];
    const float myps = lo[0] + lo[1] + lo[2] + lo[3];
    ps[tid] = myps;
    float myps2 = 0.f;
    if (tid < 25) {
        f32x4 v = ((const f32x4*)srow)[256 + tid];
        myps2 = v[0] + v[1] + v[2] + v[3];
        ps[256 + tid] = myps2;
    }
    __syncthreads();

    qs[tid] = myps + ps[tid + 1] + ps[tid + 2] + ps[tid + 3];
    if (tid < 22)
        qs[256 + tid] = myps2 + ps[257 + tid] + ps[258 + tid] + ps[259 + tid];
    __syncthreads();

    {
        float s = ps[tid + 24];
        #pragma unroll
        for (int i = 0; i < 6; ++i) s += qs[tid + 4 * i];   // ps[tid..tid+23]
        f32x4 hi = ((const f32x4*)srow)[tid + 25];
        float s1 = s  + hi[0] - lo[0];
        float s2 = s1 + hi[1] - lo[1];
        float s3 = s2 + hi[2] - lo[2];

        const int w0   = tid * 4;
        const int tile = w0 >> 7;          // 0..7
        const int c    = w0 & 127;         // multiple of 4, h4 never crosses tile
        _Float16* dst = Tt + (((size_t)b * 8 + tile) * H_IN + row) * TROW + c;
        *(h4*)dst = h4{ (_Float16)s, (_Float16)s1, (_Float16)s2, (_Float16)s3 };

        if (tid == 255) {                  // col 1024 -> slim array
            float t = ps[280];
            #pragma unroll
            for (int i = 0; i < 6; ++i) t += qs[256 + 4 * i];
            Tc[(size_t)b * H_IN + row] = (_Float16)t;
        }
    }
}

// ---------------- Pass V: sequential tile-band walk -------------------------
// grid (4 tile-pairs, NBANDS, g), block 128. Wave w handles tile 2*tp+w;
// thread owns 2 cols (f16x2 per row = 4 B; wave-instr = 256 B = one tile row,
// rows CONTIGUOUS in memory). tp==3/tid==127 also owns col 1024 via Tc.
__global__ __launch_bounds__(128) void vslide_kernel(
    const _Float16* __restrict__ Tt, // [g][8][1124][128]
    const _Float16* __restrict__ Tc, // [g][1124]
    float* __restrict__ out)         // [g][1025][1025]
{
    const int tid  = threadIdx.x;
    const int tp   = blockIdx.x;
    const int band = blockIdx.y;
    const int b    = blockIdx.z;
    const int r0   = band * BANDR;
    const int nr   = min(BANDR, H_OUT - r0);
    if (nr <= 0) return;

    const int tile = tp * 2 + (tid >> 6);
    const int cp   = tid & 63;
    const int gc   = tile * TROW + 2 * cp;
    const bool xtra = (tp == 3) && (tid == 127);
    const float scale = 1.0f / (float)(KWIN * KWIN);

    const _Float16* base  = Tt + (((size_t)b * 8 + tile) * H_IN + r0) * TROW + 2 * cp;
    const _Float16* basec = Tc + (size_t)b * H_IN + r0;

    float s0 = 0.f, s1 = 0.f, s8 = 0.f;

    // ---- prologue: rows r0..r0+99, batch-8 independent 4B loads ----
    {
        const _Float16* p  = base;
        const _Float16* pc = basec;
        for (int cg = 0; cg < 12; ++cg) {            // 96 rows
            f16x2 v[8];
            #pragma unroll
            for (int j = 0; j < 8; ++j)
                v[j] = *(const f16x2*)(p + (size_t)j * TROW);
            _Float16 vc[8];
            if (xtra) {
                #pragma unroll
                for (int j = 0; j < 8; ++j) vc[j] = pc[j];
            }
            #pragma unroll
            for (int j = 0; j < 8; ++j) {
                s0 += (float)v[j][0]; s1 += (float)v[j][1];
            }
            if (xtra) {
                #pragma unroll
                for (int j = 0; j < 8; ++j) s8 += (float)vc[j];
            }
            p += (size_t)8 * TROW; pc += 8;
        }
        #pragma unroll
        for (int j = 0; j < 4; ++j) {                // 4 remaining rows
            f16x2 v = *(const f16x2*)(p + (size_t)j * TROW);
            s0 += (float)v[0]; s1 += (float)v[1];
            if (xtra) s8 += (float)pc[j];
        }
    }

    float* q = out + ((size_t)b * H_OUT + r0) * W_OUT + gc;
    __builtin_nontemporal_store(s0 * scale, q + 0);
    __builtin_nontemporal_store(s1 * scale, q + 1);
    if (xtra) __builtin_nontemporal_store(s8 * scale, q + 2);   // col 1024
    q += W_OUT;

    // ---- steady: add row r0+100+i, sub row r0+i; batch-8 ----
    const _Float16* pa  = base  + (size_t)KWIN * TROW;
    const _Float16* pd  = base;
    const _Float16* pac = basec + KWIN;
    const _Float16* pdc = basec;
    const int steps = nr - 1;
    int i = 0;
    for (; i + 8 <= steps; i += 8) {
        f16x2 a[8], d[8];
        #pragma unroll
        for (int j = 0; j < 8; ++j) {
            a[j] = *(const f16x2*)(pa + (size_t)j * TROW);
            d[j] = *(const f16x2*)(pd + (size_t)j * TROW);
        }
        _Float16 ac[8], dc[8];
        if (xtra) {
            #pragma unroll
            for (int j = 0; j < 8; ++j) { ac[j] = pac[j]; dc[j] = pdc[j]; }
        }
        #pragma unroll
        for (int j = 0; j < 8; ++j) {
            s0 += (float)a[j][0] - (float)d[j][0];
            s1 += (float)a[j][1] - (float)d[j][1];
            __builtin_nontemporal_store(s0 * scale, q + 0);
            __builtin_nontemporal_store(s1 * scale, q + 1);
            if (xtra) {
                s8 += (float)ac[j] - (float)dc[j];
                __builtin_nontemporal_store(s8 * scale, q + 2);
            }
            q += W_OUT;
        }
        pa += (size_t)8 * TROW; pd += (size_t)8 * TROW;
        pac += 8; pdc += 8;
    }
    for (; i < steps; ++i) {
        f16x2 a = *(const f16x2*)pa, d = *(const f16x2*)pd;
        s0 += (float)a[0] - (float)d[0];
        s1 += (float)a[1] - (float)d[1];
        __builtin_nontemporal_store(s0 * scale, q + 0);
        __builtin_nontemporal_store(s1 * scale, q + 1);
        if (xtra) {
            s8 += (float)*pac - (float)*pdc;
            ++pac; ++pdc;
            __builtin_nontemporal_store(s8 * scale, q + 2);
        }
        pa += TROW; pd += TROW; q += W_OUT;
    }
}

extern "C" void kernel_launch(void* const* d_in, const int* in_sizes, int n_in,
                              void* d_out, int out_size, void* d_ws, size_t ws_size,
                              hipStream_t stream) {
    const float* x = (const float*)d_in[0];
    float* out     = (float*)d_out;
    _Float16* ws   = (_Float16*)d_ws;

    const int B = 32;
    // per-batch: 8*1124*128 halves (tiles) + 1124 halves (col-1024 slim)
    const size_t perBatchH = (size_t)8 * H_IN * TROW + H_IN;       // halves
    int G = (int)(ws_size / (perBatchH * sizeof(_Float16)));
    if (G > B) G = B;
    if (G < 1) G = 1;

    _Float16* Tt = ws;
    _Float16* Tc = ws + (size_t)G * 8 * H_IN * TROW;   // fixed offset per slice

    for (int b0 = 0; b0 < B; b0 += G) {
        const int g = (B - b0 < G) ? (B - b0) : G;

        dim3 hgrid(H_IN, g);
        hslide_kernel<<<hgrid, 256, 0, stream>>>(
            x + (size_t)b0 * H_IN * W_IN, Tt, Tc);

        dim3 vgrid(4, NBANDS, g);
        vslide_kernel<<<vgrid, 128, 0, stream>>>(
            Tt, Tc, out + (size_t)b0 * H_OUT * W_OUT);
    }
}

// Round 15
// 105.266 us; speedup vs baseline: 1.9450x; 1.0283x over previous
//
#include <hip/hip_runtime.h>

// 100x100 sliding mean over x[32][1][1124][1124] f32 -> out[32][1][1025][1025] f32.
// Pass H: horizontal 100-sum via three-level LDS partials (R9-validated) ->
//   T' TILED: [b][4 tiles][1124 rows][256 cols] f16 (tile row = 512 B),
//   plus slim Tc[b][1124] for column 1024.
// Pass V: vertical 100-sum + 1e-4 scale. One wave per tile-band: thread owns
//   4 cols (f16x4 = 8 B/lane), so each load instr covers EXACTLY one 512-B
//   tile row, byte-sequential down the band (R14 proved sequential beats
//   strided; this round doubles per-lane width 4->8 B to match hslide's
//   high-efficiency signature).

#define H_IN    1124
#define W_IN    1124
#define KWIN    100
#define W_OUT   1025
#define H_OUT   1025
#define NBANDS  6
#define BANDR   171    // 6*171 = 1026 >= 1025 (last band 170)
#define TROW    256    // tile width in halves (512 B)
#define NTILE   4

typedef float    f32x4 __attribute__((ext_vector_type(4)));
typedef _Float16 f16x4 __attribute__((ext_vector_type(4)));

struct alignas(8) h4 { _Float16 a, b, c, d; };

// ---------------- Pass H: one block per input row, tiled f16 T output -------
// grid (H_IN, g), block 256.
__global__ __launch_bounds__(256) void hslide_kernel(
    const float* __restrict__ x,     // [g][1124][1124]
    _Float16* __restrict__ Tt,       // [g][4][1124][256]
    _Float16* __restrict__ Tc)       // [g][1124]
{
    __shared__ float srow[W_IN];
    __shared__ float ps[284];        // ps[j] = srow[4j..4j+3], j < 281
    __shared__ float qs[280];        // qs[j] = ps[j]+..+ps[j+3]

    const int row = blockIdx.x;
    const int b   = blockIdx.y;
    const int tid = threadIdx.x;
    const f32x4* xr4 = (const f32x4*)(x + ((size_t)b * H_IN + row) * W_IN);

    for (int i = tid; i < 281; i += 256)
        ((f32x4*)srow)[i] = __builtin_nontemporal_load(xr4 + i);
    __syncthreads();

    f32x4 lo = ((const f32x4*)srow)[tid];
    const float myps = lo[0] + lo[1] + lo[2] + lo[3];
    ps[tid] = myps;
    float myps2 = 0.f;
    if (tid < 25) {
        f32x4 v = ((const f32x4*)srow)[256 + tid];
        myps2 = v[0] + v[1] + v[2] + v[3];
        ps[256 + tid] = myps2;
    }
    __syncthreads();

    qs[tid] = myps + ps[tid + 1] + ps[tid + 2] + ps[tid + 3];
    if (tid < 22)
        qs[256 + tid] = myps2 + ps[257 + tid] + ps[258 + tid] + ps[259 + tid];
    __syncthreads();

    {
        float s = ps[tid + 24];
        #pragma unroll
        for (int i = 0; i < 6; ++i) s += qs[tid + 4 * i];   // ps[tid..tid+23]
        f32x4 hi = ((const f32x4*)srow)[tid + 25];
        float s1 = s  + hi[0] - lo[0];
        float s2 = s1 + hi[1] - lo[1];
        float s3 = s2 + hi[2] - lo[2];

        const int w0   = tid * 4;
        const int tile = w0 >> 8;          // 0..3
        const int c    = w0 & 255;         // multiple of 4; h4 never crosses tile
        _Float16* dst = Tt + (((size_t)b * NTILE + tile) * H_IN + row) * TROW + c;
        *(h4*)dst = h4{ (_Float16)s, (_Float16)s1, (_Float16)s2, (_Float16)s3 };

        if (tid == 255) {                  // col 1024 -> slim array
            float t = ps[280];
            #pragma unroll
            for (int i = 0; i < 6; ++i) t += qs[256 + 4 * i];
            Tc[(size_t)b * H_IN + row] = (_Float16)t;
        }
    }
}

// ---------------- Pass V: one wave per tile-band, 8 B/lane sequential -------
// grid (NTILE, NBANDS, g), block 64. Thread owns cols tile*256+4*tid..+3;
// tile 3 / tid 63 additionally owns col 1024 via Tc.
__global__ __launch_bounds__(64) void vslide_kernel(
    const _Float16* __restrict__ Tt, // [g][4][1124][256]
    const _Float16* __restrict__ Tc, // [g][1124]
    float* __restrict__ out)         // [g][1025][1025]
{
    const int tid  = threadIdx.x;        // 0..63
    const int tile = blockIdx.x;         // 0..3
    const int band = blockIdx.y;
    const int b    = blockIdx.z;
    const int r0   = band * BANDR;
    const int nr   = min(BANDR, H_OUT - r0);
    if (nr <= 0) return;

    const int gc    = tile * TROW + 4 * tid;
    const bool xtra = (tile == 3) && (tid == 63);       // gc == 1020
    const float scale = 1.0f / (float)(KWIN * KWIN);

    const _Float16* base  = Tt + (((size_t)b * NTILE + tile) * H_IN + r0) * TROW
                          + 4 * tid;
    const _Float16* basec = Tc + (size_t)b * H_IN + r0;

    float s0 = 0.f, s1 = 0.f, s2 = 0.f, s3 = 0.f, s8 = 0.f;

    // ---- prologue: rows r0..r0+99, batch-8 independent 8B loads ----
    {
        const _Float16* p  = base;
        const _Float16* pc = basec;
        for (int cg = 0; cg < 12; ++cg) {            // 96 rows
            f16x4 v[8];
            #pragma unroll
            for (int j = 0; j < 8; ++j)
                v[j] = *(const f16x4*)(p + (size_t)j * TROW);
            _Float16 vc[8];
            if (xtra) {
                #pragma unroll
                for (int j = 0; j < 8; ++j) vc[j] = pc[j];
            }
            #pragma unroll
            for (int j = 0; j < 8; ++j) {
                s0 += (float)v[j][0]; s1 += (float)v[j][1];
                s2 += (float)v[j][2]; s3 += (float)v[j][3];
            }
            if (xtra) {
                #pragma unroll
                for (int j = 0; j < 8; ++j) s8 += (float)vc[j];
            }
            p += (size_t)8 * TROW; pc += 8;
        }
        #pragma unroll
        for (int j = 0; j < 4; ++j) {                // 4 remaining rows
            f16x4 v = *(const f16x4*)(p + (size_t)j * TROW);
            s0 += (float)v[0]; s1 += (float)v[1];
            s2 += (float)v[2]; s3 += (float)v[3];
            if (xtra) s8 += (float)pc[j];
        }
    }

    float* q = out + ((size_t)b * H_OUT + r0) * W_OUT + gc;
    __builtin_nontemporal_store(s0 * scale, q + 0);
    __builtin_nontemporal_store(s1 * scale, q + 1);
    __builtin_nontemporal_store(s2 * scale, q + 2);
    __builtin_nontemporal_store(s3 * scale, q + 3);
    if (xtra) __builtin_nontemporal_store(s8 * scale, q + 4);   // col 1024
    q += W_OUT;

    // ---- steady: add row r0+100+i, sub row r0+i; batch-4 (8 loads deep) ----
    const _Float16* pa  = base  + (size_t)KWIN * TROW;
    const _Float16* pd  = base;
    const _Float16* pac = basec + KWIN;
    const _Float16* pdc = basec;
    const int steps = nr - 1;
    int i = 0;
    for (; i + 4 <= steps; i += 4) {
        f16x4 a[4], d[4];
        #pragma unroll
        for (int j = 0; j < 4; ++j) {
            a[j] = *(const f16x4*)(pa + (size_t)j * TROW);
            d[j] = *(const f16x4*)(pd + (size_t)j * TROW);
        }
        _Float16 ac[4], dc[4];
        if (xtra) {
            #pragma unroll
            for (int j = 0; j < 4; ++j) { ac[j] = pac[j]; dc[j] = pdc[j]; }
        }
        #pragma unroll
        for (int j = 0; j < 4; ++j) {
            s0 += (float)a[j][0] - (float)d[j][0];
            s1 += (float)a[j][1] - (float)d[j][1];
            s2 += (float)a[j][2] - (float)d[j][2];
            s3 += (float)a[j][3] - (float)d[j][3];
            __builtin_nontemporal_store(s0 * scale, q + 0);
            __builtin_nontemporal_store(s1 * scale, q + 1);
            __builtin_nontemporal_store(s2 * scale, q + 2);
            __builtin_nontemporal_store(s3 * scale, q + 3);
            if (xtra) {
                s8 += (float)ac[j] - (float)dc[j];
                __builtin_nontemporal_store(s8 * scale, q + 4);
            }
            q += W_OUT;
        }
        pa += (size_t)4 * TROW; pd += (size_t)4 * TROW;
        pac += 4; pdc += 4;
    }
    for (; i < steps; ++i) {
        f16x4 a = *(const f16x4*)pa, d = *(const f16x4*)pd;
        s0 += (float)a[0] - (float)d[0];
        s1 += (float)a[1] - (float)d[1];
        s2 += (float)a[2] - (float)d[2];
        s3 += (float)a[3] - (float)d[3];
        __builtin_nontemporal_store(s0 * scale, q + 0);
        __builtin_nontemporal_store(s1 * scale, q + 1);
        __builtin_nontemporal_store(s2 * scale, q + 2);
        __builtin_nontemporal_store(s3 * scale, q + 3);
        if (xtra) {
            s8 += (float)*pac - (float)*pdc;
            ++pac; ++pdc;
            __builtin_nontemporal_store(s8 * scale, q + 4);
        }
        pa += TROW; pd += TROW; q += W_OUT;
    }
}

extern "C" void kernel_launch(void* const* d_in, const int* in_sizes, int n_in,
                              void* d_out, int out_size, void* d_ws, size_t ws_size,
                              hipStream_t stream) {
    const float* x = (const float*)d_in[0];
    float* out     = (float*)d_out;
    _Float16* ws   = (_Float16*)d_ws;

    const int B = 32;
    // per-batch: 4*1124*256 halves (tiles) + 1124 halves (col-1024 slim)
    const size_t perBatchH = (size_t)NTILE * H_IN * TROW + H_IN;   // halves
    int G = (int)(ws_size / (perBatchH * sizeof(_Float16)));
    if (G > B) G = B;
    if (G < 1) G = 1;

    _Float16* Tt = ws;
    _Float16* Tc = ws + (size_t)G * NTILE * H_IN * TROW;

    for (int b0 = 0; b0 < B; b0 += G) {
        const int g = (B - b0 < G) ? (B - b0) : G;

        dim3 hgrid(H_IN, g);
        hslide_kernel<<<hgrid, 256, 0, stream>>>(
            x + (size_t)b0 * H_IN * W_IN, Tt, Tc);

        dim3 vgrid(NTILE, NBANDS, g);
        vslide_kernel<<<vgrid, 64, 0, stream>>>(
            Tt, Tc, out + (size_t)b0 * H_OUT * W_OUT);
    }
}